// Round 9
// baseline (408.879 us; speedup 1.0000x reference)
//
#include <hip/hip_runtime.h>
#include <stdint.h>

// ScoreMatching: B=2048, D=64, H=512.
// out[b] = 0.5*||s_b||^2 + tr(W4 M3 W3 M2 W2 M1 W1)_b
// div_b = sum_{i,d} m2[i] * C[i,d] * G[i,d]
//   C = W2 @ (M1 .* W1)      [512 x 64]
//   G = W3^T @ (M3 .* W4^T)  [512 x 64]
// R9 div: 2 SAMPLES PER WAVE. Raw B-frags are sample-independent (masks are
// the only per-sample part), so the same 16 KB/kc of loads now feeds 64 MFMAs
// (was 32) -> intensity 2x, flipping the kernel from vmem-return-bound
// (R4/R5/R8: MfmaUtil <=37%) to MFMA-bound. Costs 256 accumulator AGPRs ->
// needs the full 512-reg budget: __launch_bounds__(256,1) (deliberate
// exception to the R2 law; 256 acc + ~100 VGPR ~= 360 <= 512, no spill).
// Addressing: R4 index-form (R8's induction pointers regressed 164->212 us).
// Ordering law (R7): convert -> forward -> div as separate launches.

typedef __attribute__((ext_vector_type(8))) short short8;
typedef __attribute__((ext_vector_type(4))) float f32x4;

union U16x8 {
  uint4 u;
  short8 s;
};

__device__ __forceinline__ uint16_t f2bf(float f) {
  uint32_t u = __float_as_uint(f);
  uint32_t lsb = (u >> 16) & 1u;
  u += 0x7FFFu + lsb;  // round-to-nearest-even
  return (uint16_t)(u >> 16);
}

// ---------------- convert: swizzled bf16 MFMA fragments + fp32 transposes ----------------
// Fragment order (16x16x32 bf16 MFMA): lane = quad*16+l15 holds 8 contiguous
// bf16 = 16 B; A-frag elem (m=l15, k=quad*8+j); B-frag (n=l15, k=quad*8+j).
__global__ __launch_bounds__(256) void convert_kernel(
    const float* __restrict__ W1, const float* __restrict__ W2,
    const float* __restrict__ W3, const float* __restrict__ W4,
    uint16_t* __restrict__ A2swz, uint16_t* __restrict__ A3swz,
    uint16_t* __restrict__ B1swz, uint16_t* __restrict__ B4swz,
    float* __restrict__ W2Tf, float* __restrict__ W3Tf,
    float* __restrict__ W1Tf, float* __restrict__ W4Tf) {
  const int i = blockIdx.x * 256 + threadIdx.x;
  if (i < 262144) {  // A2swz = W2 frags
    const int e = i, f = e >> 3, j = e & 7;
    const int lane = f & 63, fk = f >> 6;
    const int kc = fk & 15, r16 = fk >> 4;
    const int l15 = lane & 15, quad = lane >> 4;
    A2swz[e] = f2bf(W2[(r16 * 16 + l15) * 512 + kc * 32 + quad * 8 + j]);
  } else if (i < 524288) {  // A3swz = W3^T frags
    const int e = i - 262144, f = e >> 3, j = e & 7;
    const int lane = f & 63, fk = f >> 6;
    const int kc = fk & 15, r16 = fk >> 4;
    const int l15 = lane & 15, quad = lane >> 4;
    A3swz[e] = f2bf(W3[(kc * 32 + quad * 8 + j) * 512 + r16 * 16 + l15]);
  } else if (i < 557056) {  // B1swz = W1^T frags
    const int e = i - 524288, f = e >> 3, j = e & 7;
    const int lane = f & 63, fk = f >> 6;
    const int kc = fk >> 2, jt = fk & 3;
    const int l15 = lane & 15, quad = lane >> 4;
    B1swz[e] = f2bf(W1[(kc * 32 + quad * 8 + j) * 64 + jt * 16 + l15]);
  } else if (i < 589824) {  // B4swz = W4 frags
    const int e = i - 557056, f = e >> 3, j = e & 7;
    const int lane = f & 63, fk = f >> 6;
    const int kc = fk >> 2, jt = fk & 3;
    const int l15 = lane & 15, quad = lane >> 4;
    B4swz[e] = f2bf(W4[(jt * 16 + l15) * 512 + kc * 32 + quad * 8 + j]);
  } else if (i < 851968) {  // W2Tf [k][j]
    const int e = i - 589824;
    W2Tf[e] = W2[(e & 511) * 512 + (e >> 9)];
  } else if (i < 1114112) {  // W3Tf [k][j]
    const int e = i - 851968;
    W3Tf[e] = W3[(e & 511) * 512 + (e >> 9)];
  } else if (i < 1146880) {  // W1Tf [k][j], k<64
    const int e = i - 1114112;
    W1Tf[e] = W1[(e & 511) * 64 + (e >> 9)];
  } else if (i < 1179648) {  // W4Tf [k][d]
    const int e = i - 1146880;
    W4Tf[e] = W4[(e & 63) * 512 + (e >> 6)];
  }
}

// ---------------- forward (fp32): packed masks + 0.5*||s||^2 ----------------
// 256 blocks x 512 threads (8 waves = 2 waves/SIMD for latency hiding).
// Thread: sg = t>>8 (sample group of 4), q = t&255 -> units 2q, 2q+1.
// Per k: one wave-uniform LDS float4 (4 samples) + coalesced global float2
// (2 units) -> 8 FMA. Masks: 2 bits per (thread,sample) -> LDS atomicOr;
// bit u of word w = unit w*32+u (the layout div_kernel consumes).
__global__ __launch_bounds__(512) void forward_kernel(
    const float* __restrict__ x,
    const float* __restrict__ W1Tf, const float* __restrict__ b1,
    const float* __restrict__ W2Tf, const float* __restrict__ b2,
    const float* __restrict__ W3Tf, const float* __restrict__ b3,
    const float* __restrict__ W4Tf, const float* __restrict__ b4,
    uint32_t* __restrict__ m1p, uint32_t* __restrict__ m2p,
    uint32_t* __restrict__ m3p, float* __restrict__ out) {
  __shared__ float4 xs[2][64];      // [group][k]
  __shared__ float4 hp[2][2][512];  // [buf][group][unit]
  __shared__ uint32_t mw[128];      // [sample][16 words]
  const int t = threadIdx.x;
  const int b0 = blockIdx.x * 8;
  const int sg = t >> 8, q = t & 255;
  const int j2 = q * 2;
  const int word = j2 >> 5, bitpos = j2 & 31;

  {
    // stage x: 8 samples x 64 k; thread t: s = t>>6, k = t&63 (coalesced)
    const int s = t >> 6, k = t & 63;
    ((float*)&xs[s >> 2][k])[s & 3] = x[(size_t)(b0 + s) * 64 + k];
    if (t < 128) mw[t] = 0;
  }
  __syncthreads();

  float a[2][4];  // [unit][sample]

#define FWD_LAYER(WT, BIAS, SRC, DSTBUF, MGLOB, KDIM)                          \
  {                                                                            \
    const float2 bb = *(const float2*)((BIAS) + j2);                           \
    _Pragma("unroll") for (int si = 0; si < 4; ++si) {                         \
      a[0][si] = bb.x; a[1][si] = bb.y;                                        \
    }                                                                          \
    _Pragma("unroll 8") for (int k = 0; k < (KDIM); ++k) {                     \
      const float2 w = *(const float2*)((WT) + (size_t)k * 512 + j2);          \
      const float4 h = (SRC)[k];                                               \
      a[0][0] = fmaf(w.x, h.x, a[0][0]); a[0][1] = fmaf(w.x, h.y, a[0][1]);    \
      a[0][2] = fmaf(w.x, h.z, a[0][2]); a[0][3] = fmaf(w.x, h.w, a[0][3]);    \
      a[1][0] = fmaf(w.y, h.x, a[1][0]); a[1][1] = fmaf(w.y, h.y, a[1][1]);    \
      a[1][2] = fmaf(w.y, h.z, a[1][2]); a[1][3] = fmaf(w.y, h.w, a[1][3]);    \
    }                                                                          \
    _Pragma("unroll") for (int si = 0; si < 4; ++si) {                         \
      uint32_t bits = (a[0][si] > 0.f ? 1u : 0u) | (a[1][si] > 0.f ? 2u : 0u); \
      if (bits) atomicOr(&mw[(sg * 4 + si) * 16 + word], bits << bitpos);      \
    }                                                                          \
    hp[DSTBUF][sg][j2] =                                                       \
        make_float4(a[0][0] > 0.f ? a[0][0] : 0.f,                             \
                    a[0][1] > 0.f ? a[0][1] : 0.f,                             \
                    a[0][2] > 0.f ? a[0][2] : 0.f,                             \
                    a[0][3] > 0.f ? a[0][3] : 0.f);                            \
    hp[DSTBUF][sg][j2 + 1] =                                                   \
        make_float4(a[1][0] > 0.f ? a[1][0] : 0.f,                             \
                    a[1][1] > 0.f ? a[1][1] : 0.f,                             \
                    a[1][2] > 0.f ? a[1][2] : 0.f,                             \
                    a[1][3] > 0.f ? a[1][3] : 0.f);                            \
    __syncthreads();                                                           \
    if (t < 128) {                                                             \
      (MGLOB)[(size_t)(b0 + (t >> 4)) * 16 + (t & 15)] = mw[t];                \
      mw[t] = 0;                                                               \
    }                                                                          \
    __syncthreads();                                                           \
  }

  FWD_LAYER(W1Tf, b1, xs[sg], 0, m1p, 64)
  FWD_LAYER(W2Tf, b2, hp[0][sg], 1, m2p, 512)
  FWD_LAYER(W3Tf, b3, hp[1][sg], 0, m3p, 512)
#undef FWD_LAYER

  // ---- layer 4 (K=512, D=64) + 0.5*||s||^2 : wave wv -> sample b0+wv ----
  {
    const int sidx = t >> 6, d = t & 63;
    const int gg = sidx >> 2, comp = sidx & 3;
    float acc = b4[d];
#pragma unroll 8
    for (int k = 0; k < 512; ++k) {
      const float h = ((const float*)&hp[0][gg][k])[comp];
      acc = fmaf(W4Tf[k * 64 + d], h, acc);
    }
    float sq = acc * acc;
#pragma unroll
    for (int off = 32; off; off >>= 1) sq += __shfl_down(sq, off, 64);
    if (d == 0) out[b0 + sidx] = 0.5f * sq;
  }
}

// ---------------- divergence: 2-samples-per-wave dual bf16 MFMA stream ----------------
// grid (256 sample-octets, 8 row-slices of 64); block 256 = 4 waves.
// ALL waves in a block cover rows r0..r0+63; wave wv handles samples
// blockIdx.x*8 + 2*wv and +1. A- and raw-B-frags are identical across the
// block's waves (L1-hot) and across samples (masks applied in-register).
// Per wave per kc: 16 coalesced 1KB loads -> 64 MFMAs.
__global__ __launch_bounds__(256, 1) void div_kernel(
    const uint4* __restrict__ A2swz, const uint4* __restrict__ A3swz,
    const uint4* __restrict__ B1swz, const uint4* __restrict__ B4swz,
    const uint32_t* __restrict__ m1p, const uint32_t* __restrict__ m2p,
    const uint32_t* __restrict__ m3p, float* __restrict__ out) {
  const int t = threadIdx.x;
  const int lane = t & 63, wv = t >> 6;
  const int l15 = lane & 15, quad = lane >> 4;
  const int r0 = blockIdx.y * 64;
  const int s0 = blockIdx.x * 8 + wv * 2;  // this wave: samples s0, s0+1
  const int r16b = r0 >> 4;

  f32x4 aC0[4][4], aG0[4][4], aC1[4][4], aG1[4][4];
#pragma unroll
  for (int it = 0; it < 4; ++it)
#pragma unroll
    for (int jt = 0; jt < 4; ++jt) {
      aC0[it][jt] = (f32x4){0.f, 0.f, 0.f, 0.f};
      aG0[it][jt] = (f32x4){0.f, 0.f, 0.f, 0.f};
      aC1[it][jt] = (f32x4){0.f, 0.f, 0.f, 0.f};
      aG1[it][jt] = (f32x4){0.f, 0.f, 0.f, 0.f};
    }

  const uint32_t* m1a = m1p + (size_t)s0 * 16;
  const uint32_t* m3a = m3p + (size_t)s0 * 16;

#pragma unroll 1
  for (int kc = 0; kc < 16; ++kc) {
    uint4 a2[4], u1[4], a3[4], u4[4];
#pragma unroll
    for (int it = 0; it < 4; ++it)
      a2[it] = A2swz[(size_t)((r16b + it) * 16 + kc) * 64 + lane];
#pragma unroll
    for (int jt = 0; jt < 4; ++jt)
      u1[jt] = B1swz[(size_t)(kc * 4 + jt) * 64 + lane];
#pragma unroll
    for (int it = 0; it < 4; ++it)
      a3[it] = A3swz[(size_t)((r16b + it) * 16 + kc) * 64 + lane];
#pragma unroll
    for (int jt = 0; jt < 4; ++jt)
      u4[jt] = B4swz[(size_t)(kc * 4 + jt) * 64 + lane];

    // wave-uniform masks for both samples: 8 bits -> 4 dwords of bf16 AND-masks
    const uint32_t m1d0 = __builtin_amdgcn_readfirstlane(m1a[kc]);
    const uint32_t m1d1 = __builtin_amdgcn_readfirstlane(m1a[16 + kc]);
    const uint32_t m3d0 = __builtin_amdgcn_readfirstlane(m3a[kc]);
    const uint32_t m3d1 = __builtin_amdgcn_readfirstlane(m3a[16 + kc]);
    uint32_t k10[4], k11[4], k30[4], k31[4];
#pragma unroll
    for (int i = 0; i < 4; ++i) {
      const uint32_t b10 = (m1d0 >> (quad * 8)) & 0xFFu;
      const uint32_t b11 = (m1d1 >> (quad * 8)) & 0xFFu;
      const uint32_t b30 = (m3d0 >> (quad * 8)) & 0xFFu;
      const uint32_t b31 = (m3d1 >> (quad * 8)) & 0xFFu;
      k10[i] = (((b10 >> (2 * i)) & 1u) ? 0x0000FFFFu : 0u) |
               (((b10 >> (2 * i + 1)) & 1u) ? 0xFFFF0000u : 0u);
      k11[i] = (((b11 >> (2 * i)) & 1u) ? 0x0000FFFFu : 0u) |
               (((b11 >> (2 * i + 1)) & 1u) ? 0xFFFF0000u : 0u);
      k30[i] = (((b30 >> (2 * i)) & 1u) ? 0x0000FFFFu : 0u) |
               (((b30 >> (2 * i + 1)) & 1u) ? 0xFFFF0000u : 0u);
      k31[i] = (((b31 >> (2 * i)) & 1u) ? 0x0000FFFFu : 0u) |
               (((b31 >> (2 * i + 1)) & 1u) ? 0xFFFF0000u : 0u);
    }

#define MFMA_PASS(ACC, AFRAG, URAW, MK)                                        \
  {                                                                            \
    short8 bf[4];                                                              \
    _Pragma("unroll") for (int jt = 0; jt < 4; ++jt) {                         \
      U16x8 u;                                                                 \
      u.u = URAW[jt];                                                          \
      u.u.x &= MK[0]; u.u.y &= MK[1]; u.u.z &= MK[2]; u.u.w &= MK[3];          \
      bf[jt] = u.s;                                                            \
    }                                                                          \
    _Pragma("unroll") for (int it = 0; it < 4; ++it) {                         \
      U16x8 ua;                                                                \
      ua.u = AFRAG[it];                                                        \
      const short8 af = ua.s;                                                  \
      _Pragma("unroll") for (int jt = 0; jt < 4; ++jt)                         \
          ACC[it][jt] = __builtin_amdgcn_mfma_f32_16x16x32_bf16(               \
              af, bf[jt], ACC[it][jt], 0, 0, 0);                               \
    }                                                                          \
  }

    MFMA_PASS(aC0, a2, u1, k10)
    MFMA_PASS(aC1, a2, u1, k11)
    MFMA_PASS(aG0, a3, u4, k30)
    MFMA_PASS(aG1, a3, u4, k31)
#undef MFMA_PASS
  }

  // epilogue: dsum_s = sum m2_s[row] * C .* G ; C/D: row = quad*4+reg, col = l15
  float ds0 = 0.f, ds1 = 0.f;
#pragma unroll
  for (int it = 0; it < 4; ++it) {
    const int rloc = it * 16 + quad * 4;      // 0..60 within 64-row slice
    const int widx = (r0 + rloc) >> 5;
    const int shft = rloc & 31;               // r0 % 32 == 0
    const uint32_t bits0 = (m2p[(size_t)s0 * 16 + widx] >> shft) & 0xFu;
    const uint32_t bits1 = (m2p[(size_t)(s0 + 1) * 16 + widx] >> shft) & 0xFu;
#pragma unroll
    for (int jt = 0; jt < 4; ++jt) {
#pragma unroll
      for (int r = 0; r < 4; ++r) {
        const float w0 = (bits0 >> r) & 1u ? 1.f : 0.f;
        const float w1 = (bits1 >> r) & 1u ? 1.f : 0.f;
        ds0 = fmaf(w0, aC0[it][jt][r] * aG0[it][jt][r], ds0);
        ds1 = fmaf(w1, aC1[it][jt][r] * aG1[it][jt][r], ds1);
      }
    }
  }
#pragma unroll
  for (int off = 32; off; off >>= 1) {
    ds0 += __shfl_down(ds0, off, 64);
    ds1 += __shfl_down(ds1, off, 64);
  }
  if (lane == 0) {
    atomicAdd(out + s0, ds0);
    atomicAdd(out + s0 + 1, ds1);
  }
}

extern "C" void kernel_launch(void* const* d_in, const int* in_sizes, int n_in,
                              void* d_out, int out_size, void* d_ws, size_t ws_size,
                              hipStream_t stream) {
  const float* x  = (const float*)d_in[0];
  const float* W1 = (const float*)d_in[1];
  const float* b1 = (const float*)d_in[2];
  const float* W2 = (const float*)d_in[3];
  const float* b2 = (const float*)d_in[4];
  const float* W3 = (const float*)d_in[5];
  const float* b3 = (const float*)d_in[6];
  const float* W4 = (const float*)d_in[7];
  const float* b4 = (const float*)d_in[8];
  float* out = (float*)d_out;

  // workspace layout (bytes), total 3,932,160:
  char* ws = (char*)d_ws;
  uint16_t* A2swz = (uint16_t*)(ws + 0);        // 524288
  uint16_t* A3swz = (uint16_t*)(ws + 524288);   // 524288
  uint16_t* B1swz = (uint16_t*)(ws + 1048576);  // 65536
  uint16_t* B4swz = (uint16_t*)(ws + 1114112);  // 65536
  float*    W2Tf  = (float*)(ws + 1179648);     // 1048576
  float*    W3Tf  = (float*)(ws + 2228224);     // 1048576
  float*    W1Tf  = (float*)(ws + 3276800);     // 131072
  float*    W4Tf  = (float*)(ws + 3407872);     // 131072
  uint32_t* m1p   = (uint32_t*)(ws + 3538944);  // 131072 (2048 x 512 bits)
  uint32_t* m2p   = (uint32_t*)(ws + 3670016);  // 131072
  uint32_t* m3p   = (uint32_t*)(ws + 3801088);  // 131072
  if (ws_size < 3932160) return;

  convert_kernel<<<4608, 256, 0, stream>>>(W1, W2, W3, W4,
                                           A2swz, A3swz, B1swz, B4swz,
                                           W2Tf, W3Tf, W1Tf, W4Tf);
  forward_kernel<<<256, 512, 0, stream>>>(x, W1Tf, b1, W2Tf, b2, W3Tf, b3,
                                          W4Tf, b4, m1p, m2p, m3p, out);
  div_kernel<<<dim3(256, 8), 256, 0, stream>>>((const uint4*)A2swz,
                                               (const uint4*)A3swz,
                                               (const uint4*)B1swz,
                                               (const uint4*)B4swz,
                                               m1p, m2p, m3p, out);
}